// Round 1
// baseline (1394.917 us; speedup 1.0000x reference)
//
#include <hip/hip_runtime.h>
#include <hip/hip_bf16.h>
#include <math.h>

// ---------------------------------------------------------------------------
// Problem constants (from reference)
// ---------------------------------------------------------------------------
#define OUT_H 7
#define OUT_W 35
#define NBINS (OUT_H * OUT_W)   // 245
#define NCH   256
#define NROI  512
#define NLVL  4

// Per-level H=W, pixel-site offsets into the NHWC bf16 workspace
//   level pixel sites: l0 2*256*256=131072, l1 2*128*128=32768,
//   l2 2*64*64=8192, l3 2*32*32=2048  (total 174080 sites * 256ch * 2B = 89.1MB)

// ---------------------------------------------------------------------------
// Kernel 1: NCHW fp32 -> NHWC bf16 transpose (per level), 64x64 LDS tile
// grid: (HW/64, C/64=4, B=2), block 256
// ---------------------------------------------------------------------------
__global__ __launch_bounds__(256) void transpose_nchw_to_nhwc(
    const float* __restrict__ in, __hip_bfloat16* __restrict__ out, int HW) {
  __shared__ float tile[64][65];  // +1 pad: conflict-free transposed reads
  const int x   = threadIdx.x & 63;
  const int y4  = threadIdx.x >> 6;  // 0..3
  const int hw0 = blockIdx.x << 6;
  const int c0  = blockIdx.y << 6;
  const int b   = blockIdx.z;

  const float* src = in + ((size_t)(b * NCH + c0)) * HW + hw0;
#pragma unroll
  for (int i = 0; i < 16; ++i) {
    int row = (i << 2) + y4;  // channel offset within tile
    tile[row][x] = src[(size_t)row * HW + x];
  }
  __syncthreads();
  __hip_bfloat16* dst = out + ((size_t)(b * HW + hw0)) * NCH + c0;
#pragma unroll
  for (int i = 0; i < 16; ++i) {
    int row = (i << 2) + y4;  // hw offset within tile
    dst[(size_t)row * NCH + x] = __float2bfloat16(tile[x][row]);
  }
}

// ---------------------------------------------------------------------------
// Kernel 2: rotated RoIAlign gather + 2x2 mean + max over levels
// grid: (OUT_H, NROI), block 256 (thread = channel)
// ---------------------------------------------------------------------------
__global__ __launch_bounds__(256) void roi_align_rotated_max(
    const ushort* __restrict__ ft,   // NHWC bf16 (as ushort bits), all levels
    const float* __restrict__ rois,  // [512][6]
    float* __restrict__ out)         // [512][256][7][35]
{
  __shared__ int   s_off[OUT_W][16];     //  2240 B
  __shared__ float s_wt[OUT_W][16][4];   //  8960 B
  __shared__ float s_out[NCH * OUT_W];   // 35840 B   (total 47040 B)

  const int oh = blockIdx.x;
  const int n  = blockIdx.y;
  const float* R = rois + n * 6;
  const int   b     = (int)R[0];
  const float theta = R[5];
  // cos/sin via double -> correctly-rounded f32 (validity boundary is
  // discontinuous; match numpy's f32 transcendentals as closely as possible)
  const float ct = (float)cos((double)theta);
  const float st = (float)sin((double)theta);

  // ---- Phase 1: sample descriptors (offset + 4 pre-scaled weights) ----
  for (int j = threadIdx.x; j < OUT_W * 16; j += 256) {
    const int ow = j >> 4;
    const int ls = j & 15;
    const int l  = ls >> 2;
    const int s  = ls & 3;
    const int sy = s >> 1, sx = s & 1;

    const int   Hl     = 256 >> l;  // W == H per level
    const float scale  = 0.25f / (float)(1 << l);
    const int   pixoff = (l == 0) ? 0 : (l == 1) ? 131072 : (l == 2) ? 163840 : 172032;

    // mirror reference f32 op order exactly; no FMA contraction
    const float cx = __fmul_rn(R[1], scale);
    const float cy = __fmul_rn(R[2], scale);
    const float w  = fmaxf(__fmul_rn(R[3], scale), 1.0f);
    const float h  = fmaxf(__fmul_rn(R[4], scale), 1.0f);
    const float bin_h = __fdiv_rn(h, (float)OUT_H);
    const float bin_w = __fdiv_rn(w, (float)OUT_W);
    const float gy = (float)oh + (sy ? 0.75f : 0.25f);
    const float gx = (float)ow + (sx ? 0.75f : 0.25f);
    const float yy = __fadd_rn(__fmul_rn(-h, 0.5f), __fmul_rn(gy, bin_h));
    const float xx = __fadd_rn(__fmul_rn(-w, 0.5f), __fmul_rn(gx, bin_w));
    const float x = __fadd_rn(__fsub_rn(__fmul_rn(xx, ct), __fmul_rn(yy, st)), cx);
    const float y = __fadd_rn(__fadd_rn(__fmul_rn(xx, st), __fmul_rn(yy, ct)), cy);

    const bool valid = (y >= -1.0f) && (y <= (float)Hl) &&
                       (x >= -1.0f) && (x <= (float)Hl);
    float yc = fminf(fmaxf(y, 0.0f), (float)(Hl - 1));
    float xc = fminf(fmaxf(x, 0.0f), (float)(Hl - 1));
    int y0 = (int)floorf(yc);
    int x0 = (int)floorf(xc);
    float ly = yc - (float)y0;
    float lx = xc - (float)x0;
    // edge identity: (y0=H-1, ly=0) == (y0=H-2, ly=1): keeps y1=y0+1 in-bounds
    if (y0 >= Hl - 1) { y0 = Hl - 2; ly = 1.0f; }
    if (x0 >= Hl - 1) { x0 = Hl - 2; lx = 1.0f; }
    const float hy = 1.0f - ly, hx = 1.0f - lx;
    const float sc = valid ? 0.25f : 0.0f;  // fold sample mean (1/ns^2)

    s_off[ow][ls]   = pixoff + (b * Hl + y0) * Hl + x0;
    s_wt[ow][ls][0] = sc * hy * hx;
    s_wt[ow][ls][1] = sc * hy * lx;
    s_wt[ow][ls][2] = sc * ly * hx;
    s_wt[ow][ls][3] = sc * ly * lx;
  }
  __syncthreads();

  // ---- Phase 2: channel gather (lanes = channels, coalesced 128B/wave) ----
  const int c = threadIdx.x;
  for (int ow = 0; ow < OUT_W; ++ow) {
    float vl[NLVL];
#pragma unroll
    for (int l = 0; l < NLVL; ++l) {
      const int Wrow = (256 >> l) * NCH;  // row stride in elements
      float v = 0.0f;
#pragma unroll
      for (int s = 0; s < 4; ++s) {
        const int ls = (l << 2) | s;
        const int base = s_off[ow][ls] * NCH + c;  // LDS broadcast
        const float w0 = s_wt[ow][ls][0];
        const float w1 = s_wt[ow][ls][1];
        const float w2 = s_wt[ow][ls][2];
        const float w3 = s_wt[ow][ls][3];
        const float f00 = __uint_as_float((unsigned)ft[base] << 16);
        const float f01 = __uint_as_float((unsigned)ft[base + NCH] << 16);
        const float f10 = __uint_as_float((unsigned)ft[base + Wrow] << 16);
        const float f11 = __uint_as_float((unsigned)ft[base + Wrow + NCH] << 16);
        v = fmaf(w0, f00, fmaf(w1, f01, fmaf(w2, f10, fmaf(w3, f11, v))));
      }
      vl[l] = v;
    }
    // stride 35 over lanes: 2-way LDS bank aliasing only (free per m136)
    s_out[c * OUT_W + ow] = fmaxf(fmaxf(vl[0], vl[1]), fmaxf(vl[2], vl[3]));
  }
  __syncthreads();

  // ---- Phase 3: near-coalesced output write (runs of 140B per channel) ----
  const size_t outbase = (size_t)n * NCH * NBINS + (size_t)oh * OUT_W;
  for (int u = threadIdx.x; u < NCH * OUT_W; u += 256) {
    const int cc = u / OUT_W;
    const int ww = u - cc * OUT_W;
    out[outbase + (size_t)cc * NBINS + ww] = s_out[u];
  }
}

// ---------------------------------------------------------------------------
extern "C" void kernel_launch(void* const* d_in, const int* in_sizes, int n_in,
                              void* d_out, int out_size, void* d_ws, size_t ws_size,
                              hipStream_t stream) {
  const float* feats[4] = {(const float*)d_in[0], (const float*)d_in[1],
                           (const float*)d_in[2], (const float*)d_in[3]};
  const float* rois = (const float*)d_in[4];
  __hip_bfloat16* ws = (__hip_bfloat16*)d_ws;
  float* out = (float*)d_out;

  const int HWs[4] = {256 * 256, 128 * 128, 64 * 64, 32 * 32};
  const size_t pixoff[4] = {0, 131072, 163840, 172032};

  for (int l = 0; l < 4; ++l) {
    dim3 grid(HWs[l] / 64, NCH / 64, 2);
    transpose_nchw_to_nhwc<<<grid, 256, 0, stream>>>(feats[l],
                                                     ws + pixoff[l] * NCH,
                                                     HWs[l]);
  }
  dim3 grid2(OUT_H, NROI);
  roi_align_rotated_max<<<grid2, 256, 0, stream>>>((const ushort*)ws, rois, out);
}

// Round 2
// 529.488 us; speedup vs baseline: 2.6345x; 2.6345x over previous
//
#include <hip/hip_runtime.h>
#include <hip/hip_bf16.h>
#include <math.h>

// ---------------------------------------------------------------------------
// Problem constants
// ---------------------------------------------------------------------------
#define OUT_H 7
#define OUT_W 35
#define NBINS (OUT_H * OUT_W)   // 245
#define NCH   256
#define NROI  512

// NHWC bf16 workspace pixel-site offsets per level (site = 256 ch = 512 B):
//   l0: 0, l1: 131072, l2: 163840, l3: 172032   (total 174080 sites = 89.1 MB)

__device__ __forceinline__ float blo(unsigned u) { return __uint_as_float(u << 16); }
__device__ __forceinline__ float bhi(unsigned u) { return __uint_as_float(u & 0xffff0000u); }

// ---------------------------------------------------------------------------
// Kernel 1: all-level NCHW fp32 -> NHWC bf16 transpose, one launch.
// Flat grid of 64ch x 64hw tiles: l0 8192, l1 2048, l2 512, l3 128 = 10880.
// ---------------------------------------------------------------------------
__global__ __launch_bounds__(256) void transpose_all(
    const float* __restrict__ f0, const float* __restrict__ f1,
    const float* __restrict__ f2, const float* __restrict__ f3,
    ushort* __restrict__ ws)
{
  __shared__ float tile[64][65];  // pitch 65: ~2-way bank aliasing both phases

  const int t = blockIdx.x;
  int l, rel;
  if      (t < 8192)  { l = 0; rel = t; }
  else if (t < 10240) { l = 1; rel = t - 8192; }
  else if (t < 10752) { l = 2; rel = t - 10240; }
  else                { l = 3; rel = t - 10752; }

  const int HWl = (256 * 256) >> (2 * l);
  const int lg  = 10 - 2 * l;          // log2(HWl/64)
  const int hwT = rel & ((1 << lg) - 1);
  const int tmp = rel >> lg;
  const int cT  = tmp & 3;
  const int b   = tmp >> 2;
  const float* fsrc = (l == 0) ? f0 : (l == 1) ? f1 : (l == 2) ? f2 : f3;
  const int pixoff  = (l == 0) ? 0 : (l == 1) ? 131072 : (l == 2) ? 163840 : 172032;
  const int hw0 = hwT << 6;
  const int c0  = cT << 6;

  // ---- load: float4, thread = (channel row, quarter) ----
  const int cl = threadIdx.x >> 2;  // 0..63
  const int g  = threadIdx.x & 3;   // 0..3
  const float* srcp = fsrc + ((size_t)(b * NCH + c0 + cl)) * HWl + hw0;
#pragma unroll
  for (int k = 0; k < 4; ++k) {
    const int hw = 4 * (g + 4 * k);
    const float4 v = *(const float4*)(srcp + hw);
    tile[cl][hw + 0] = v.x; tile[cl][hw + 1] = v.y;
    tile[cl][hw + 2] = v.z; tile[cl][hw + 3] = v.w;
  }
  __syncthreads();

  // ---- store: ushort4 (4 consecutive channels), lanes sweep channels ----
  const int cq  = threadIdx.x & 15;  // channel group 0..15 -> c = cq*4
  const int hwl = threadIdx.x >> 4;  // 0..15
#pragma unroll
  for (int j = 0; j < 4; ++j) {
    const int hw = hwl + 16 * j;
    ushort4 u;
    {
      __hip_bfloat16 h0 = __float2bfloat16(tile[cq * 4 + 0][hw]);
      __hip_bfloat16 h1 = __float2bfloat16(tile[cq * 4 + 1][hw]);
      __hip_bfloat16 h2 = __float2bfloat16(tile[cq * 4 + 2][hw]);
      __hip_bfloat16 h3 = __float2bfloat16(tile[cq * 4 + 3][hw]);
      u.x = *(ushort*)&h0; u.y = *(ushort*)&h1;
      u.z = *(ushort*)&h2; u.w = *(ushort*)&h3;
    }
    *(ushort4*)(ws + ((size_t)(pixoff + b * HWl + hw0 + hw)) * NCH + c0 + cq * 4) = u;
  }
}

// ---------------------------------------------------------------------------
// Kernel 2: rotated RoIAlign gather + 2x2 mean + max over levels.
// grid (7, 512), block 256 = 4 waves. Lane = 4 channels (uint2 gather loads,
// 512 B/wave). Wave w handles ow = w, w+4, ... Output staged in LDS in two
// halves (18+17 ow) so total LDS ~29.8 KB -> 5 blocks/CU.
// ---------------------------------------------------------------------------
__global__ __launch_bounds__(256, 5) void roi_align_rotated_max(
    const ushort* __restrict__ ft,   // NHWC bf16 (bits), all levels
    const float* __restrict__ rois,  // [512][6]
    float* __restrict__ out)         // [512][256][7][35]
{
  __shared__ int    s_off[OUT_W * 16];  //  2240 B (byte offset of (y0,x0) site)
  __shared__ float4 s_wt[OUT_W * 16];   //  8960 B (4 pre-scaled tap weights)
  __shared__ float  s_out[18 * 258];    // 18576 B (pitch 258: b64-aligned, 2-way banks)

  const int oh = blockIdx.x;
  const int n  = blockIdx.y;
  const float* R = rois + n * 6;
  const int b = (int)R[0];
  // cos/sin via double -> correctly-rounded f32 (validity test is discontinuous)
  const float ct = (float)cos((double)R[5]);
  const float st = (float)sin((double)R[5]);

  // ---- Phase 1: 560 sample descriptors ----
  for (int j = threadIdx.x; j < OUT_W * 16; j += 256) {
    const int ow = j >> 4;
    const int ls = j & 15;
    const int l  = ls >> 2;
    const int s  = ls & 3;
    const int sy = s >> 1, sx = s & 1;

    const int   Hl     = 256 >> l;
    const float scale  = 0.25f / (float)(1 << l);
    const int   pixoff = (l == 0) ? 0 : (l == 1) ? 131072 : (l == 2) ? 163840 : 172032;

    // mirror reference f32 op order exactly; no FMA contraction
    const float cx = __fmul_rn(R[1], scale);
    const float cy = __fmul_rn(R[2], scale);
    const float w  = fmaxf(__fmul_rn(R[3], scale), 1.0f);
    const float h  = fmaxf(__fmul_rn(R[4], scale), 1.0f);
    const float bin_h = __fdiv_rn(h, (float)OUT_H);
    const float bin_w = __fdiv_rn(w, (float)OUT_W);
    const float gy = (float)oh + (sy ? 0.75f : 0.25f);
    const float gx = (float)ow + (sx ? 0.75f : 0.25f);
    const float yy = __fadd_rn(__fmul_rn(-h, 0.5f), __fmul_rn(gy, bin_h));
    const float xx = __fadd_rn(__fmul_rn(-w, 0.5f), __fmul_rn(gx, bin_w));
    const float x = __fadd_rn(__fsub_rn(__fmul_rn(xx, ct), __fmul_rn(yy, st)), cx);
    const float y = __fadd_rn(__fadd_rn(__fmul_rn(xx, st), __fmul_rn(yy, ct)), cy);

    const bool valid = (y >= -1.0f) && (y <= (float)Hl) &&
                       (x >= -1.0f) && (x <= (float)Hl);
    float yc = fminf(fmaxf(y, 0.0f), (float)(Hl - 1));
    float xc = fminf(fmaxf(x, 0.0f), (float)(Hl - 1));
    int y0 = (int)floorf(yc);
    int x0 = (int)floorf(xc);
    float ly = yc - (float)y0;
    float lx = xc - (float)x0;
    // edge identity: (y0=H-1,ly=0) == (y0=H-2,ly=1): y1,x1 stay in-bounds
    if (y0 >= Hl - 1) { y0 = Hl - 2; ly = 1.0f; }
    if (x0 >= Hl - 1) { x0 = Hl - 2; lx = 1.0f; }
    const float hy = 1.0f - ly, hx = 1.0f - lx;
    const float sc = valid ? 0.25f : 0.0f;  // fold 1/ns^2 sample mean

    s_off[j] = (pixoff + (b * Hl + y0) * Hl + x0) * (NCH * 2);  // byte offset
    s_wt[j]  = make_float4(sc * hy * hx, sc * hy * lx, sc * ly * hx, sc * ly * lx);
  }
  __syncthreads();

  const int  wv   = threadIdx.x >> 6;
  const int  lane = threadIdx.x & 63;
  const char* ftb = (const char*)ft + lane * 8;  // 4 channels / lane
  const size_t outrow = (size_t)n * NCH * NBINS + (size_t)oh * OUT_W;

#pragma unroll
  for (int half = 0; half < 2; ++half) {
    const int base = half ? 18 : 0;
    const int cnt  = half ? 17 : 18;

    for (int ow = base + wv; ow < base + cnt; ow += 4) {
      float m0, m1, m2, m3;
#pragma unroll
      for (int l = 0; l < 4; ++l) {
        const int rowb = (256 >> l) * (NCH * 2);  // compile-time row stride
        float v0 = 0.f, v1 = 0.f, v2 = 0.f, v3 = 0.f;
#pragma unroll
        for (int s = 0; s < 4; ++s) {
          const int d = ow * 16 + l * 4 + s;
          const char* p = ftb + s_off[d];
          const float4 w = s_wt[d];
          const uint2 A = *(const uint2*)(p);               // (y0,x0)
          const uint2 B = *(const uint2*)(p + 512);         // (y0,x1)
          const uint2 C = *(const uint2*)(p + rowb);        // (y1,x0)
          const uint2 D = *(const uint2*)(p + rowb + 512);  // (y1,x1)
          v0 = fmaf(w.x, blo(A.x), v0); v0 = fmaf(w.y, blo(B.x), v0);
          v0 = fmaf(w.z, blo(C.x), v0); v0 = fmaf(w.w, blo(D.x), v0);
          v1 = fmaf(w.x, bhi(A.x), v1); v1 = fmaf(w.y, bhi(B.x), v1);
          v1 = fmaf(w.z, bhi(C.x), v1); v1 = fmaf(w.w, bhi(D.x), v1);
          v2 = fmaf(w.x, blo(A.y), v2); v2 = fmaf(w.y, blo(B.y), v2);
          v2 = fmaf(w.z, blo(C.y), v2); v2 = fmaf(w.w, blo(D.y), v2);
          v3 = fmaf(w.x, bhi(A.y), v3); v3 = fmaf(w.y, bhi(B.y), v3);
          v3 = fmaf(w.z, bhi(C.y), v3); v3 = fmaf(w.w, bhi(D.y), v3);
        }
        if (l == 0) { m0 = v0; m1 = v1; m2 = v2; m3 = v3; }
        else {
          m0 = fmaxf(m0, v0); m1 = fmaxf(m1, v1);
          m2 = fmaxf(m2, v2); m3 = fmaxf(m3, v3);
        }
      }
      float* so = &s_out[(ow - base) * 258 + lane * 4];
      so[0] = m0; so[1] = m1; so[2] = m2; so[3] = m3;
    }
    __syncthreads();

    // near-coalesced transposed write-out of this half
    if (half == 0) {
#pragma unroll
      for (int j = 0; j < 18; ++j) {
        const int idx = threadIdx.x + j * 256;   // 0..4607
        const int cc  = idx / 18;                // const-divisor magic mul
        const int ww  = idx - cc * 18;
        out[outrow + (size_t)cc * NBINS + ww] = s_out[ww * 258 + cc];
      }
    } else {
#pragma unroll
      for (int j = 0; j < 17; ++j) {
        const int idx = threadIdx.x + j * 256;   // 0..4351
        const int cc  = idx / 17;
        const int ww  = idx - cc * 17;
        out[outrow + 18 + (size_t)cc * NBINS + ww] = s_out[ww * 258 + cc];
      }
    }
    __syncthreads();
  }
}

// ---------------------------------------------------------------------------
extern "C" void kernel_launch(void* const* d_in, const int* in_sizes, int n_in,
                              void* d_out, int out_size, void* d_ws, size_t ws_size,
                              hipStream_t stream) {
  const float* f0 = (const float*)d_in[0];
  const float* f1 = (const float*)d_in[1];
  const float* f2 = (const float*)d_in[2];
  const float* f3 = (const float*)d_in[3];
  const float* rois = (const float*)d_in[4];
  ushort* ws = (ushort*)d_ws;
  float* out = (float*)d_out;

  transpose_all<<<10880, 256, 0, stream>>>(f0, f1, f2, f3, ws);

  dim3 grid2(OUT_H, NROI);
  roi_align_rotated_max<<<grid2, 256, 0, stream>>>(ws, rois, out);
}

// Round 4
// 497.255 us; speedup vs baseline: 2.8052x; 1.0648x over previous
//
#include <hip/hip_runtime.h>
#include <hip/hip_bf16.h>
#include <math.h>

#define OUT_H 7
#define OUT_W 35
#define NBINS (OUT_H * OUT_W)   // 245
#define NCH   256
#define NROI  512

// NHWC f16 workspace site offsets per level (site = 256 ch = 512 B):
//   l0: 0, l1: 131072, l2: 163840, l3: 172032  (174080 sites = 89.1 MB)

typedef _Float16 h2_t __attribute__((ext_vector_type(2)));

static __device__ __forceinline__ h2_t as_h2(unsigned u) {
  return __builtin_bit_cast(h2_t, u);
}
static __device__ __forceinline__ unsigned h2_bits(h2_t v) {
  return __builtin_bit_cast(unsigned, v);
}
static __device__ __forceinline__ unsigned pkrtz_bits(float a, float b) {
  return __builtin_bit_cast(unsigned, __builtin_amdgcn_cvt_pkrtz(a, b));
}
static __device__ __forceinline__ unsigned dup16(float w) {
  _Float16 h = (_Float16)w;  // RTN
  unsigned short bts = __builtin_bit_cast(unsigned short, h);
  return (unsigned)bts * 0x10001u;
}

// ---------------------------------------------------------------------------
// Kernel 1: NCHW fp32 -> NHWC f16, tile = 64 ch x 128 hw.
// Reads: 2 x 512 B contiguous segments per wave-instr. LDS pitch 129 (odd) ->
// transposed b32 reads are 2-way (free); writes 4-way (1.58x, minor).
// Stores: uint2 (4ch f16) -> 4 full 128 B lines per wave-instr.
// ---------------------------------------------------------------------------
__global__ __launch_bounds__(256) void transpose_all(
    const float* __restrict__ f0, const float* __restrict__ f1,
    const float* __restrict__ f2, const float* __restrict__ f3,
    ushort* __restrict__ ws)
{
  __shared__ float tile[64 * 129];  // 33 KB

  const int t = blockIdx.x;
  int l, rel;
  if      (t < 4096) { l = 0; rel = t; }
  else if (t < 5120) { l = 1; rel = t - 4096; }
  else if (t < 5376) { l = 2; rel = t - 5120; }
  else               { l = 3; rel = t - 5376; }

  const int HWl  = 65536 >> (2 * l);
  const int lg   = 9 - 2 * l;            // log2(HWl/128)
  const int hwT  = rel & ((1 << lg) - 1);
  const int rest = rel >> lg;
  const int cT   = rest & 3;
  const int b    = rest >> 2;
  const float* fsrc = (l == 0) ? f0 : (l == 1) ? f1 : (l == 2) ? f2 : f3;
  const int pixoff  = (l == 0) ? 0 : (l == 1) ? 131072 : (l == 2) ? 163840 : 172032;
  const int hw0 = hwT << 7;
  const int c0  = cT << 6;

  // ---- read: float4, 2 rows x 512 B contiguous per wave-instr ----
  const int hwq = threadIdx.x & 31;
  const int r0  = threadIdx.x >> 5;  // 0..7
#pragma unroll
  for (int i = 0; i < 8; ++i) {
    const int r = r0 + 8 * i;
    const float4 v = *(const float4*)(fsrc +
        ((size_t)(b * NCH + c0 + r)) * HWl + hw0 + 4 * hwq);
    float* tp = &tile[r * 129 + 4 * hwq];
    tp[0] = v.x; tp[1] = v.y; tp[2] = v.z; tp[3] = v.w;
  }
  __syncthreads();

  // ---- write: transposed reads (2-way) + pkrtz + uint2 stores ----
  const int cq  = threadIdx.x & 15;   // channel quad
  const int hwl = threadIdx.x >> 4;   // 0..15
  ushort* wp = ws + ((size_t)(pixoff + b * HWl + hw0)) * NCH + c0 + cq * 4;
#pragma unroll
  for (int j = 0; j < 8; ++j) {
    const int hw = hwl + 16 * j;
    const float a0 = tile[(4 * cq + 0) * 129 + hw];
    const float a1 = tile[(4 * cq + 1) * 129 + hw];
    const float a2 = tile[(4 * cq + 2) * 129 + hw];
    const float a3 = tile[(4 * cq + 3) * 129 + hw];
    *(uint2*)(wp + (size_t)hw * NCH) =
        make_uint2(pkrtz_bits(a0, a1), pkrtz_bits(a2, a3));
  }
}

// ---------------------------------------------------------------------------
// Kernel 2: rotated RoIAlign gather + mean + max over levels, f16 packed math.
// 1-D grid 3584 swizzled so roi n's 7 oh-blocks share blockIdx%8 (same XCD).
// Lane = 4 channels; all tap FMAs are v_pk_fma_f16.
// ---------------------------------------------------------------------------
__global__ __launch_bounds__(256, 5) void roi_align_rotated_max(
    const ushort* __restrict__ ft,   // NHWC f16 (bits), all levels
    const float* __restrict__ rois,  // [512][6]
    float* __restrict__ out)         // [512][256][7][35]
{
  __shared__ int      s_off[OUT_W * 16];   //  2240 B
  __shared__ uint4    s_wt[OUT_W * 16];    //  8960 B (4 dup-half2 weights)
  __shared__ unsigned s_out[OUT_W * 134];  // 18760 B (f16, pitch 268 halves)

  const int g    = blockIdx.x;
  const int slot = g & 7;
  const int rest = g >> 3;
  const int oh   = rest % 7;
  const int n    = slot + 8 * (rest / 7);

  const float* R = rois + n * 6;
  const int b = (int)R[0];
  const float ct = (float)cos((double)R[5]);
  const float st = (float)sin((double)R[5]);

  // ---- Phase 1: 560 sample descriptors ----
  for (int j = threadIdx.x; j < OUT_W * 16; j += 256) {
    const int ow = j >> 4;
    const int ls = j & 15;
    const int l  = ls >> 2;
    const int s  = ls & 3;
    const int sy = s >> 1, sx = s & 1;

    const int   Hl     = 256 >> l;
    const float scale  = 0.25f / (float)(1 << l);
    const int   pixoff = (l == 0) ? 0 : (l == 1) ? 131072 : (l == 2) ? 163840 : 172032;

    // mirror reference f32 op order exactly; no FMA contraction
    const float cx = __fmul_rn(R[1], scale);
    const float cy = __fmul_rn(R[2], scale);
    const float w  = fmaxf(__fmul_rn(R[3], scale), 1.0f);
    const float h  = fmaxf(__fmul_rn(R[4], scale), 1.0f);
    const float bin_h = __fdiv_rn(h, (float)OUT_H);
    const float bin_w = __fdiv_rn(w, (float)OUT_W);
    const float gy = (float)oh + (sy ? 0.75f : 0.25f);
    const float gx = (float)ow + (sx ? 0.75f : 0.25f);
    const float yy = __fadd_rn(__fmul_rn(-h, 0.5f), __fmul_rn(gy, bin_h));
    const float xx = __fadd_rn(__fmul_rn(-w, 0.5f), __fmul_rn(gx, bin_w));
    const float x = __fadd_rn(__fsub_rn(__fmul_rn(xx, ct), __fmul_rn(yy, st)), cx);
    const float y = __fadd_rn(__fadd_rn(__fmul_rn(xx, st), __fmul_rn(yy, ct)), cy);

    const bool valid = (y >= -1.0f) && (y <= (float)Hl) &&
                       (x >= -1.0f) && (x <= (float)Hl);
    float yc = fminf(fmaxf(y, 0.0f), (float)(Hl - 1));
    float xc = fminf(fmaxf(x, 0.0f), (float)(Hl - 1));
    int y0 = (int)floorf(yc);
    int x0 = (int)floorf(xc);
    float ly = yc - (float)y0;
    float lx = xc - (float)x0;
    if (y0 >= Hl - 1) { y0 = Hl - 2; ly = 1.0f; }
    if (x0 >= Hl - 1) { x0 = Hl - 2; lx = 1.0f; }
    const float hy = 1.0f - ly, hx = 1.0f - lx;
    const float sc = valid ? 0.25f : 0.0f;  // fold 1/ns^2 sample mean

    s_off[j] = (pixoff + (b * Hl + y0) * Hl + x0) * (NCH * 2);  // byte offset
    s_wt[j]  = make_uint4(dup16(sc * hy * hx), dup16(sc * hy * lx),
                          dup16(sc * ly * hx), dup16(sc * ly * lx));
  }
  __syncthreads();

  const int  wv   = threadIdx.x >> 6;
  const int  lane = threadIdx.x & 63;
  const char* ftb = (const char*)ft + lane * 8;  // 4 channels / lane

  for (int ow = wv; ow < OUT_W; ow += 4) {
    h2_t m0, m1;
#pragma unroll
    for (int l = 0; l < 4; ++l) {
      const int rowb = 131072 >> l;  // (256>>l)*512 bytes
      h2_t a0 = {(_Float16)0, (_Float16)0};
      h2_t a1 = {(_Float16)0, (_Float16)0};
#pragma unroll
      for (int s = 0; s < 4; ++s) {
        const int d = ow * 16 + l * 4 + s;
        const char* p = ftb + s_off[d];
        const uint4 wq = s_wt[d];
        const uint2 A = *(const uint2*)(p);               // (y0,x0)
        const uint2 B = *(const uint2*)(p + 512);         // (y0,x1)
        const uint2 C = *(const uint2*)(p + rowb);        // (y1,x0)
        const uint2 D = *(const uint2*)(p + rowb + 512);  // (y1,x1)
        a0 = as_h2(wq.x) * as_h2(A.x) + a0;  a1 = as_h2(wq.x) * as_h2(A.y) + a1;
        a0 = as_h2(wq.y) * as_h2(B.x) + a0;  a1 = as_h2(wq.y) * as_h2(B.y) + a1;
        a0 = as_h2(wq.z) * as_h2(C.x) + a0;  a1 = as_h2(wq.z) * as_h2(C.y) + a1;
        a0 = as_h2(wq.w) * as_h2(D.x) + a0;  a1 = as_h2(wq.w) * as_h2(D.y) + a1;
      }
      if (l == 0) { m0 = a0; m1 = a1; }
      else {
        m0 = __builtin_elementwise_max(m0, a0);
        m1 = __builtin_elementwise_max(m1, a1);
      }
    }
    *(uint2*)&s_out[ow * 134 + lane * 2] = make_uint2(h2_bits(m0), h2_bits(m1));
  }
  __syncthreads();

  // ---- near-coalesced transposed write-out (f16 -> f32) ----
  const size_t outrow = (size_t)n * NCH * NBINS + (size_t)oh * OUT_W;
  const _Float16* sh = (const _Float16*)s_out;
#pragma unroll
  for (int j = 0; j < OUT_W; ++j) {
    const int idx = threadIdx.x + j * 256;  // 0..8959
    const int cc  = idx / OUT_W;            // magic-mul const div
    const int ww  = idx - cc * OUT_W;
    out[outrow + (size_t)cc * NBINS + ww] = (float)sh[ww * 268 + cc];
  }
}

// ---------------------------------------------------------------------------
extern "C" void kernel_launch(void* const* d_in, const int* in_sizes, int n_in,
                              void* d_out, int out_size, void* d_ws, size_t ws_size,
                              hipStream_t stream) {
  const float* f0 = (const float*)d_in[0];
  const float* f1 = (const float*)d_in[1];
  const float* f2 = (const float*)d_in[2];
  const float* f3 = (const float*)d_in[3];
  const float* rois = (const float*)d_in[4];
  ushort* ws = (ushort*)d_ws;
  float* out = (float*)d_out;

  transpose_all<<<5440, 256, 0, stream>>>(f0, f1, f2, f3, ws);
  roi_align_rotated_max<<<3584, 256, 0, stream>>>(ws, rois, out);
}